// Round 17
// baseline (126.445 us; speedup 1.0000x reference)
//
#include <hip/hip_runtime.h>
#include <stdint.h>

typedef __bf16 bf16_t;
typedef bf16_t bf16x8 __attribute__((ext_vector_type(8)));
typedef float f32x4 __attribute__((ext_vector_type(4)));
typedef uint32_t u32x4 __attribute__((ext_vector_type(4)));
typedef uint16_t u16x8 __attribute__((ext_vector_type(8)));

union FragU { u32x4 u; bf16x8 v; u16x8 s; };

__device__ __forceinline__ uint16_t f2bf_rne(float f) {
  uint32_t u = __float_as_uint(f);
  return (uint16_t)((u + 0x7fffu + ((u >> 16) & 1u)) >> 16);
}

// ---------------------------------------------------------------------------
// Kernel 1: pack W (512x52 f32) into MFMA B-fragment layout, single bf16.
// B-frag for mfma_f32_16x16x32_bf16: lane l holds B[k][n], n = nt*16+(l&15),
// k = kc*32 + (l>>4)*8 + j. N padded 52->64. ws: wf[4096] u32x4 (64 KB).
// ---------------------------------------------------------------------------
__global__ __launch_bounds__(256) void pack_w_kernel(
    const float* __restrict__ W, u32x4* __restrict__ wf) {
  int idx = blockIdx.x * 256 + threadIdx.x;
  if (idx >= 4096) return;
  int lane = idx & 63;
  int nt   = (idx >> 6) & 3;
  int ks   = idx >> 8;
  int n  = nt * 16 + (lane & 15);
  int kb = ks * 32 + (lane >> 4) * 8;
  FragU hi;
#pragma unroll
  for (int j = 0; j < 8; ++j) {
    float w = (n < 52) ? W[(kb + j) * 52 + n] : 0.0f;
    hi.s[j] = f2bf_rne(w);
  }
  wf[idx] = hi.u;
}

#define MFMA16(a, b, c) __builtin_amdgcn_mfma_f32_16x16x32_bf16((a), (b), (c), 0, 0, 0)

// ---------------------------------------------------------------------------
// Kernel 2: fused GEMM + bias + softmax(13) + rule mix — K-SPLIT, FULL-ROW
// EFFECTIVE GRANULE. Block = 32 rows; wave w owns K-slice [w*128, w*128+128)
// of all 32 rows, staged ONCE: 16 x global_load_lds, each instr = 2 rows'
// contiguous 512 B runs (src slot pre-swizzled ^ (row&7); reads XOR same).
// The 4 waves' slices are temporally clustered -> DRAM sees ~2 KB/row.
// No stage<->compute barrier (wave-private). Compute: 4 K-chunks x 8 MFMA,
// B-frag register double-buffer, waits vmcnt(4)/4/4/0 from FIFO
// stage(16) < B0(4) < B1(4). Cross-wave reduce: per-wave lds_t quadrant
// (no atomics), 2 barriers. LDS: staging 64 KB (partials [4][64][36] alias).
// 2 blocks/CU, 8 waves/CU (iso-occupancy with r15 -> granule-only A/B).
// ---------------------------------------------------------------------------
__global__ __launch_bounds__(256, 2) void raven_main_kernel(
    const float* __restrict__ z, const float* __restrict__ xq,
    const u32x4* __restrict__ wfh,
    const float* __restrict__ bias, float* __restrict__ out) {
  __shared__ __align__(16) unsigned char smem[65536];  // staging / partials union
  __shared__ float lds_bias[52];

  const int tid  = threadIdx.x;
  const int wave = tid >> 6;
  const int lane = tid & 63;
  const int r  = lane & 15;   // A row within 16-tile / C col
  const int kg = lane >> 4;   // k-group (8 contiguous k per lane)

  if (tid < 52) lds_bias[tid] = bias[tid];

  const long long brow = (long long)blockIdx.x * 32;
  const float* zb = z + brow * 512;

  unsigned char* stgw = smem + wave * 16384;  // this wave's 32 rows x 512 B
  const int wslice = wave * 128;              // K-slice start (floats)

  f32x4 acc[2][4];
#pragma unroll
  for (int mt = 0; mt < 2; ++mt)
#pragma unroll
    for (int nt = 0; nt < 4; ++nt) {
      f32x4 zv = {0.0f, 0.0f, 0.0f, 0.0f};
      acc[mt][nt] = zv;
    }

  // ---- stage this wave's K-slice of all 32 rows (16 instrs, 1 KB each) ----
  {
    const int rsub = lane >> 5;        // 0..1: row within instr
    const int slot = lane & 31;        // 16 B slot within the 512 B run
#pragma unroll
    for (int i = 0; i < 16; ++i) {
      const int ri = i * 2 + rsub;
      const float* src = zb + ri * 512 + wslice + 4 * (slot ^ (ri & 7));
      __builtin_amdgcn_global_load_lds(
          (const __attribute__((address_space(1))) void*)src,
          (__attribute__((address_space(3))) void*)(stgw + i * 1024),
          16, 0, 0);
    }
  }

#define LOADB(kc_, set_)                                                        \
  {                                                                             \
    const u32x4* p_ = wfh + (kc_) * 256 + lane;                                 \
    _Pragma("unroll")                                                           \
    for (int nt_ = 0; nt_ < 4; ++nt_)                                           \
      bh[set_][nt_].u = p_[nt_ * 64];                                           \
  }

  FragU bh[2][4];
  const int kb0 = wave * 4;      // this wave's 4 global K-chunks: kb0..kb0+3
  LOADB(kb0, 0);
  LOADB(kb0 + 1, 1);

  const int swz = (r & 7) << 4;

#pragma unroll
  for (int c = 0; c < 4; ++c) {
    // FIFO: [stage16][B0..] -> c=0: vmcnt(4) leaves B1; c=1,2: vmcnt(4)
    // leaves B(c+1); c=3: vmcnt(0).
    if (c < 3) asm volatile("s_waitcnt vmcnt(4)" ::: "memory");
    else       asm volatile("s_waitcnt vmcnt(0)" ::: "memory");
    __builtin_amdgcn_sched_barrier(0);

    // A-frags: row rl = mt*16 + r, 512 B row stride, XOR swizzle
    FragU h[2];
#pragma unroll
    for (int mt = 0; mt < 2; ++mt) {
      const unsigned char* cm = stgw + (mt * 16 + r) * 512;
      f32x4 a0 = *(const f32x4*)(cm + ((c * 128 + kg * 32) ^ swz));
      f32x4 a1 = *(const f32x4*)(cm + ((c * 128 + kg * 32 + 16) ^ swz));
#pragma unroll
      for (int j = 0; j < 4; ++j) {
        h[mt].v[j]     = (bf16_t)a0[j];
        h[mt].v[4 + j] = (bf16_t)a1[j];
      }
    }

    const int cs = c & 1;
#pragma unroll
    for (int nt = 0; nt < 4; ++nt) {
      acc[0][nt] = MFMA16(h[0].v, bh[cs][nt].v, acc[0][nt]);
      acc[1][nt] = MFMA16(h[1].v, bh[cs][nt].v, acc[1][nt]);
    }
    __builtin_amdgcn_sched_barrier(0);

    if (c < 2) LOADB(kb0 + c + 2, cs);  // refill just-consumed set
  }
#undef LOADB

  // ---- cross-wave K-reduction: per-wave partial quadrants (no atomics) ----
  __syncthreads();  // all waves done with staging ds_reads

  // partials: [wave][col 64][row 36-padded], aliases staging (36864 B)
  float (*ptl)[64][36] = (float(*)[64][36])smem;
#pragma unroll
  for (int mt = 0; mt < 2; ++mt)
#pragma unroll
    for (int nt = 0; nt < 4; ++nt)
      *(f32x4*)&ptl[wave][nt * 16 + r][mt * 16 + kg * 4] = acc[mt][nt];

  __syncthreads();

  // ---- epilogue: one thread per row (32 rows), sums 4 partials ----
  // rules = [a, b-2, b-1, b+1, b+2, a-b, a+b, min, max, b+2, b+1, b-2, b-1]
  if (tid < 32) {
    const int row = tid;
    const long long grow = brow + row;
    f32x4 xa = *(const f32x4*)(xq + grow * 8);      // a, groups 0..3
    f32x4 xb = *(const f32x4*)(xq + grow * 8 + 4);  // b, groups 0..3
    f32x4 res;
#pragma unroll
    for (int g = 0; g < 4; ++g) {
      float a  = xa[g];
      float bq = xb[g];
      float l[13];
      float m = -1e30f;
#pragma unroll
      for (int u = 0; u < 13; ++u) {
        const int col = g * 13 + u;
        l[u] = (ptl[0][col][row] + ptl[1][col][row])
             + (ptl[2][col][row] + ptl[3][col][row]) + lds_bias[col];
        m = fmaxf(m, l[u]);
      }
      float s = 0.0f;
#pragma unroll
      for (int u = 0; u < 13; ++u) {
        float e = __expf(l[u] - m);
        l[u] = e;
        s += e;
      }
      float num = a * l[0]
                + (bq - 2.0f) * (l[1] + l[11])
                + (bq - 1.0f) * (l[2] + l[12])
                + (bq + 1.0f) * (l[3] + l[10])
                + (bq + 2.0f) * (l[4] + l[9])
                + (a - bq) * l[5]
                + (a + bq) * l[6]
                + fminf(a, bq) * l[7]
                + fmaxf(a, bq) * l[8];
      res[g] = num / s;
    }
    *(f32x4*)(out + grow * 4) = res;
  }
}

extern "C" void kernel_launch(void* const* d_in, const int* in_sizes, int n_in,
                              void* d_out, int out_size, void* d_ws, size_t ws_size,
                              hipStream_t stream) {
  const float* z    = (const float*)d_in[0];  // (B, 512)
  const float* xq   = (const float*)d_in[1];  // (B, 2, 4)
  const float* W    = (const float*)d_in[2];  // (512, 52)
  const float* bias = (const float*)d_in[3];  // (52,)
  float* out = (float*)d_out;                 // (B, 1, 4)

  const int B = in_sizes[0] / 512;            // 262144

  u32x4* wf = (u32x4*)d_ws;

  hipLaunchKernelGGL(pack_w_kernel, dim3(16), dim3(256), 0, stream, W, wf);

  const int blocks = B / 32;                  // 8192
  hipLaunchKernelGGL(raven_main_kernel, dim3(blocks), dim3(256), 0, stream,
                     z, xq, (const u32x4*)wf, bias, out);
}

// Round 18
// 106.092 us; speedup vs baseline: 1.1918x; 1.1918x over previous
//
#include <hip/hip_runtime.h>
#include <stdint.h>

typedef __bf16 bf16_t;
typedef bf16_t bf16x8 __attribute__((ext_vector_type(8)));
typedef float f32x2 __attribute__((ext_vector_type(2)));
typedef float f32x4 __attribute__((ext_vector_type(4)));
typedef uint32_t u32x4 __attribute__((ext_vector_type(4)));
typedef uint16_t u16x8 __attribute__((ext_vector_type(8)));

union FragU { u32x4 u; bf16x8 v; u16x8 s; };

__device__ __forceinline__ uint16_t f2bf_rne(float f) {
  uint32_t u = __float_as_uint(f);
  return (uint16_t)((u + 0x7fffu + ((u >> 16) & 1u)) >> 16);
}

// ---------------------------------------------------------------------------
// Kernel 1: pack W (512x52 f32) into MFMA B-fragment layout, single bf16.
// B-frag for mfma_f32_16x16x32_bf16: lane l holds B[k][n], n = nt*16+(l&15),
// k = ks32*32 + (l>>4)*8 + j. N padded 52->64. ws: wf[4096] u32x4 (64 KB).
// ---------------------------------------------------------------------------
__global__ __launch_bounds__(256) void pack_w_kernel(
    const float* __restrict__ W, u32x4* __restrict__ wf) {
  int idx = blockIdx.x * 256 + threadIdx.x;
  if (idx >= 4096) return;
  int lane = idx & 63;
  int nt   = (idx >> 6) & 3;
  int ks   = idx >> 8;
  int n  = nt * 16 + (lane & 15);
  int kb = ks * 32 + (lane >> 4) * 8;
  FragU hi;
#pragma unroll
  for (int j = 0; j < 8; ++j) {
    float w = (n < 52) ? W[(kb + j) * 52 + n] : 0.0f;
    hi.s[j] = f2bf_rne(w);
  }
  wf[idx] = hi.u;
}

#define MFMA16(a, b, c) __builtin_amdgcn_mfma_f32_16x16x32_bf16((a), (b), (c), 0, 0, 0)

// ---------------------------------------------------------------------------
// Kernel 2: fused GEMM + bias + softmax(13) + rule mix — BK=64, 256 B runs.
// Session-best structure (r15, 105.9 us). Staging instr covers 4 rows x
// 256 B contiguous runs; pipeline: single-wait vmcnt(16), B register
// double-buffer, double-buffered global_load_lds staging. 8 K-iters, per
// iter: 8 stage + 8 B + 16 MFMA. LDS: staging [4][2][8192]=64 KB union
// logits_t[64][132]. 2 blocks/CU, 8 waves/CU.
// ---------------------------------------------------------------------------
__global__ __launch_bounds__(256, 2) void raven_main_kernel(
    const float* __restrict__ z, const float* __restrict__ xq,
    const u32x4* __restrict__ wfh,
    const float* __restrict__ bias, float* __restrict__ out) {
  __shared__ __align__(16) unsigned char smem[65536];  // staging / logits_t union
  __shared__ float lds_bias[52];

  const int tid  = threadIdx.x;
  const int wave = tid >> 6;
  const int lane = tid & 63;
  const int r  = lane & 15;   // A row within 16-tile / C col
  const int kg = lane >> 4;   // k-group (8 contiguous k per lane)

  if (tid < 52) lds_bias[tid] = bias[tid];

  const long long brow = (long long)blockIdx.x * 128;
  const long long wrow = brow + (long long)wave * 32;
  const float* zb = z + wrow * 512;

  unsigned char* stg = smem + wave * 16384;  // [2][8192]

  // staging: instr i covers rows i*4 + (lane>>4), 16 lanes x 16 B = 256 B/row;
  // source slot pre-swizzled: s' = (lane&15) ^ (srow&7); read XORs the same.
  const int rloc4 = lane >> 4;   // 0..3: row within instr
  const int slot  = lane & 15;   // 16 B slot within the 256 B row-chunk

  f32x4 acc[2][4];
#pragma unroll
  for (int mt = 0; mt < 2; ++mt)
#pragma unroll
    for (int nt = 0; nt < 4; ++nt) {
      f32x4 zv = {0.0f, 0.0f, 0.0f, 0.0f};
      acc[mt][nt] = zv;
    }

#define STAGE_CHUNK(ks_, buf_)                                                  \
  {                                                                             \
    _Pragma("unroll")                                                           \
    for (int i_ = 0; i_ < 8; ++i_) {                                            \
      const int srow_ = i_ * 4 + rloc4;                                         \
      const int foff_ = 4 * (slot ^ (srow_ & 7));                               \
      const float* g_ = zb + srow_ * 512 + (ks_) * 64 + foff_;                  \
      __builtin_amdgcn_global_load_lds(                                         \
          (const __attribute__((address_space(1))) void*)g_,                    \
          (__attribute__((address_space(3))) void*)((buf_) + i_ * 1024),        \
          16, 0, 0);                                                            \
    }                                                                           \
  }

#define LOADB(ks_, set_)                                                        \
  {                                                                             \
    const u32x4* p0_ = wfh + (2 * (ks_)) * 256 + lane;                          \
    const u32x4* p1_ = wfh + (2 * (ks_) + 1) * 256 + lane;                      \
    _Pragma("unroll")                                                           \
    for (int nt_ = 0; nt_ < 4; ++nt_) {                                         \
      bh[set_][nt_].u     = p0_[nt_ * 64];                                      \
      bh[set_][4 + nt_].u = p1_[nt_ * 64];                                      \
    }                                                                           \
  }

  FragU bh[2][8];

  // prologue FIFO: B(0)[8] < stage(0)[8] < B(1)[8] < stage(1)[8]
  LOADB(0, 0);
  STAGE_CHUNK(0, stg);
  LOADB(1, 1);
  STAGE_CHUNK(1, stg + 8192);

  const int swz = (r & 7) << 4;

#pragma unroll
  for (int ks = 0; ks < 8; ++ks) {
    unsigned char* cur = stg + (ks & 1) * 8192;

    // single wait: drain {B(ks), stage(ks)}; B(ks+1)+stage(ks+1) in flight
    if (ks < 7) asm volatile("s_waitcnt vmcnt(16)" ::: "memory");
    else        asm volatile("s_waitcnt vmcnt(0)"  ::: "memory");
    __builtin_amdgcn_sched_barrier(0);

    // A-frags from LDS: row stride 256 B, col = c*128 + kg*32 (+16), XOR swz
    FragU h[2][2];  // [c][mt]
#pragma unroll
    for (int c = 0; c < 2; ++c)
#pragma unroll
      for (int mt = 0; mt < 2; ++mt) {
        const unsigned char* cm = cur + (mt * 16 + r) * 256;
        f32x4 a0 = *(const f32x4*)(cm + ((c * 128 + kg * 32) ^ swz));
        f32x4 a1 = *(const f32x4*)(cm + ((c * 128 + kg * 32 + 16) ^ swz));
#pragma unroll
        for (int j = 0; j < 4; ++j) {
          h[c][mt].v[j]     = (bf16_t)a0[j];
          h[c][mt].v[4 + j] = (bf16_t)a1[j];
        }
      }

    const int cs = ks & 1;
#pragma unroll
    for (int c = 0; c < 2; ++c)
#pragma unroll
      for (int nt = 0; nt < 4; ++nt) {
        acc[0][nt] = MFMA16(h[c][0].v, bh[cs][c * 4 + nt].v, acc[0][nt]);
        acc[1][nt] = MFMA16(h[c][1].v, bh[cs][c * 4 + nt].v, acc[1][nt]);
      }
    __builtin_amdgcn_sched_barrier(0);

    // issue next operands AFTER MFMAs consumed bh[cs] (overwrite it):
    // FIFO gains B(ks+2)[8] < stage(ks+2)[8], preserving the wait math.
    if (ks < 6) {
      LOADB(ks + 2, cs);
      STAGE_CHUNK(ks + 2, cur);  // cur's ds_reads retired (lgkm in-order)
    }
  }
#undef STAGE_CHUNK
#undef LOADB

  // staging area is dead only after ALL waves finish their K-loop
  __syncthreads();

  // TRANSPOSED logits tile: lds_t[col][local_row], stride 132 (pad 4).
  // C layout: col = nt*16 + r, row = wave*32 + mt*16 + kg*4 + i.
  float (*lds_t)[132] = (float(*)[132])smem;
#pragma unroll
  for (int mt = 0; mt < 2; ++mt)
#pragma unroll
    for (int nt = 0; nt < 4; ++nt)
      *(f32x4*)&lds_t[nt * 16 + r][wave * 32 + mt * 16 + kg * 4] = acc[mt][nt];

  __syncthreads();

  // Epilogue over ALL 256 threads: thread t -> row = t>>1, groups
  // gp = (t&1)*2 .. gp+1. Per group: softmax(13) + rule mix.
  // rules = [a, b-2, b-1, b+1, b+2, a-b, a+b, min, max, b+2, b+1, b-2, b-1]
  {
    const int row = tid >> 1;
    const int gp  = (tid & 1) * 2;
    const long long grow = brow + row;
    f32x2 res;
#pragma unroll
    for (int gi = 0; gi < 2; ++gi) {
      const int g = gp + gi;
      float a  = xq[grow * 8 + g];
      float bq = xq[grow * 8 + 4 + g];
      float l[13];
      float m = -1e30f;
#pragma unroll
      for (int u = 0; u < 13; ++u) {
        l[u] = lds_t[g * 13 + u][row] + lds_bias[g * 13 + u];
        m = fmaxf(m, l[u]);
      }
      float s = 0.0f;
#pragma unroll
      for (int u = 0; u < 13; ++u) {
        float e = __expf(l[u] - m);
        l[u] = e;
        s += e;
      }
      float num = a * l[0]
                + (bq - 2.0f) * (l[1] + l[11])
                + (bq - 1.0f) * (l[2] + l[12])
                + (bq + 1.0f) * (l[3] + l[10])
                + (bq + 2.0f) * (l[4] + l[9])
                + (a - bq) * l[5]
                + (a + bq) * l[6]
                + fminf(a, bq) * l[7]
                + fmaxf(a, bq) * l[8];
      res[gi] = num / s;
    }
    *(f32x2*)(out + grow * 4 + gp) = res;
  }
}

extern "C" void kernel_launch(void* const* d_in, const int* in_sizes, int n_in,
                              void* d_out, int out_size, void* d_ws, size_t ws_size,
                              hipStream_t stream) {
  const float* z    = (const float*)d_in[0];  // (B, 512)
  const float* xq   = (const float*)d_in[1];  // (B, 2, 4)
  const float* W    = (const float*)d_in[2];  // (512, 52)
  const float* bias = (const float*)d_in[3];  // (52,)
  float* out = (float*)d_out;                 // (B, 1, 4)

  const int B = in_sizes[0] / 512;            // 262144

  u32x4* wf = (u32x4*)d_ws;

  hipLaunchKernelGGL(pack_w_kernel, dim3(16), dim3(256), 0, stream, W, wf);

  const int blocks = B / 128;                 // 2048
  hipLaunchKernelGGL(raven_main_kernel, dim3(blocks), dim3(256), 0, stream,
                     z, xq, (const u32x4*)wf, bias, out);
}